// Round 8
// baseline (421.456 us; speedup 1.0000x reference)
//
#include <hip/hip_runtime.h>

// Event voxelization: events [N,4] f32 (x,y,t,p) -> vox[2*16*260*346] set-to-1.
//
// R1-R6: any random per-event fabric access costs ~32-40 B; R3's 183 us was
//        that roofline (cache hints / atomics / target size all no-ops).
// R7:    two-pass radix partition (LDS counting sort -> coalesced) broke it:
//        kernel time ~135 us. Profile also showed dur_us carries ~250 us of
//        fixed harness reset (1 GB d_ws poison @ 155 us + d_in restore).
// R8:    leaner partition: idx in REGISTERS (29/thread, no raw[] LDS array),
//        u16 within-bucket offsets (halves idx_buf traffic 64->32 MB each way),
//        LDS 60->18 KB (occupancy 2->~8 WGs/CU), wave-per-run gather in pass 2.

#define CBINS 16
#define HDIM  260
#define WDIM  346
#define NVOX  (2 * CBINS * HDIM * WDIM)   // 2,878,720
#define NBUCK 256
#define RGN   11264                        // voxels/bucket; 256*11264 >= NVOX; < 2^16
#define EPT   29                           // events per thread
#define CHUNK (EPT * 256)                  // 7424 events per pass-1 WG
#define SENT  0xFFFFFFFFu

typedef float fvec4 __attribute__((ext_vector_type(4)));

__device__ __forceinline__ unsigned ev_to_idx(fvec4 e) {
    float t = e.z;
    if (!(t > 0.f && t <= 1.f)) return SENT;
    int xi  = (int)e.x;
    int yi  = (int)e.y;
    int pi  = (e.w > 0.f) ? 1 : 0;                 // p {-1,1} -> {0,1}
    int bin = (int)ceilf(t * (float)CBINS) - 1;    // [0,15]
    return (unsigned)(xi + WDIM * yi + WDIM * HDIM * (bin + CBINS * pi));
}

// ---------------- Pass 1: partition ----------------
__global__ __launch_bounds__(256) void partition_kernel(
        const fvec4* __restrict__ ev, int n,
        unsigned short* __restrict__ idx_buf, // [nchunk*CHUNK] u16 local offsets
        unsigned* __restrict__ goff,          // [(NBUCK+1)*nchunk], bucket-major
        int nchunk) {
    __shared__ unsigned short srt[CHUNK];     // 14,848 B
    __shared__ unsigned hist[NBUCK + 1];
    __shared__ unsigned scan[NBUCK];
    __shared__ unsigned cursor[NBUCK];

    const int w = blockIdx.x, tid = threadIdx.x;
    const int base = w * CHUNK;
    const int nev = min(CHUNK, n - base);

    for (int b = tid; b <= NBUCK; b += 256) hist[b] = 0;
    __syncthreads();

    // Phase A: load events (29 independent nt loads -> MLP), idx -> REGISTERS,
    // LDS histogram. Out-of-range lanes count into the sentinel bucket.
    unsigned idx[EPT];
    #pragma unroll
    for (int it = 0; it < EPT; ++it) {
        int k = tid + it * 256;
        unsigned v = SENT;
        if (k < nev) v = ev_to_idx(__builtin_nontemporal_load(&ev[base + k]));
        idx[it] = v;
        atomicAdd(&hist[(v == SENT) ? NBUCK : v / (unsigned)RGN], 1u);
    }
    __syncthreads();

    // Phase B: inclusive scan of hist[0..255] (Hillis-Steele, 256 threads).
    unsigned v = hist[tid];
    scan[tid] = v;
    __syncthreads();
    for (int s = 1; s < 256; s <<= 1) {
        unsigned add = (tid >= s) ? scan[tid - s] : 0u;
        __syncthreads();
        scan[tid] += add;
        __syncthreads();
    }
    unsigned excl = scan[tid] - v;
    cursor[tid] = excl;
    goff[tid * nchunk + w] = excl;                        // bucket-major table
    if (tid == 255) goff[NBUCK * nchunk + w] = scan[255]; // total valid
    __syncthreads();

    // Phase C: counting-sort u16 local offsets into LDS straight from registers.
    #pragma unroll
    for (int it = 0; it < EPT; ++it) {
        unsigned vv = idx[it];
        if (vv != SENT) {
            unsigned b   = vv / (unsigned)RGN;
            unsigned pos = atomicAdd(&cursor[b], 1u);
            srt[pos] = (unsigned short)(vv - b * (unsigned)RGN);
        }
    }
    __syncthreads();

    // Phase D: coalesced contiguous chunk write (u16 pairs as u32).
    unsigned total = scan[255];
    unsigned* dst = (unsigned*)(idx_buf + (size_t)w * CHUNK); // 4B-aligned (CHUNK even)
    const unsigned* src = (const unsigned*)srt;
    for (unsigned j = tid; j < (total + 1) / 2; j += 256) dst[j] = src[j];
}

// ---------------- Pass 2: build output region ----------------
__global__ __launch_bounds__(1024) void build_kernel(
        const unsigned short* __restrict__ idx_buf,
        const unsigned* __restrict__ goff,
        fvec4* __restrict__ out, int nchunk) {
    __shared__ unsigned char flag[RGN];       // 11,264 B
    const int b = blockIdx.x, tid = threadIdx.x;
    const int wave = tid >> 6, lane = tid & 63;   // 16 waves

    for (int i = tid; i < RGN / 4; i += 1024) ((unsigned*)flag)[i] = 0;
    __syncthreads();

    const unsigned* row0 = goff + (size_t)b * nchunk;
    const unsigned* row1 = row0 + nchunk;
    // Wave-per-chunk-run: lanes gather one run cooperatively (coalesced u16s).
    for (int w = wave; w < nchunk; w += 16) {
        unsigned s = row0[w], e = row1[w];        // broadcast reads
        const unsigned short* p = idx_buf + (size_t)w * CHUNK;
        for (unsigned j = s + lane; j < e; j += 64)
            flag[p[j]] = 1;                       // LDS byte store
    }
    __syncthreads();

    for (int i = tid; i < RGN / 4; i += 1024) {
        int g = b * (RGN / 4) + i;                // float4 index
        if (g < NVOX / 4) {
            uchar4 f = ((const uchar4*)flag)[i];
            fvec4 vv = { f.x ? 1.f : 0.f, f.y ? 1.f : 0.f,
                         f.z ? 1.f : 0.f, f.w ? 1.f : 0.f };
            __builtin_nontemporal_store(vv, &out[g]);
        }
    }
}

// ---------------- Fallback (R3 path) if ws too small ----------------
__global__ __launch_bounds__(256) void scatter_flags(const fvec4* __restrict__ ev,
                                                     unsigned char* __restrict__ flags,
                                                     int n) {
    int i = blockIdx.x * blockDim.x + threadIdx.x;
    if (i >= n) return;
    unsigned idx = ev_to_idx(__builtin_nontemporal_load(&ev[i]));
    if (idx != SENT) flags[idx] = 1;
}
__global__ __launch_bounds__(256) void expand_flags(const uchar4* __restrict__ flags,
                                                    fvec4* __restrict__ out, int n4) {
    int i = blockIdx.x * blockDim.x + threadIdx.x;
    if (i >= n4) return;
    uchar4 f = flags[i];
    fvec4 v = { f.x ? 1.f : 0.f, f.y ? 1.f : 0.f, f.z ? 1.f : 0.f, f.w ? 1.f : 0.f };
    __builtin_nontemporal_store(v, &out[i]);
}

extern "C" void kernel_launch(void* const* d_in, const int* in_sizes, int n_in,
                              void* d_out, int out_size, void* d_ws, size_t ws_size,
                              hipStream_t stream) {
    const fvec4* ev = (const fvec4*)d_in[0];
    int n  = in_sizes[0] / 4;                // 16,000,000
    int n4 = out_size / 4;                   // 719,680
    int nchunk = (n + CHUNK - 1) / CHUNK;    // 2156

    size_t idx_bytes = (size_t)nchunk * CHUNK * sizeof(unsigned short);  // ~32 MB
    size_t off_bytes = (size_t)(NBUCK + 1) * nchunk * sizeof(unsigned);  // ~2.2 MB

    if (ws_size >= idx_bytes + off_bytes) {
        unsigned short* idx_buf = (unsigned short*)d_ws;
        unsigned* goff = (unsigned*)((char*)d_ws + idx_bytes);
        partition_kernel<<<nchunk, 256, 0, stream>>>(ev, n, idx_buf, goff, nchunk);
        build_kernel<<<NBUCK, 1024, 0, stream>>>(idx_buf, goff, (fvec4*)d_out, nchunk);
    } else {
        unsigned char* flags = (unsigned char*)d_ws;
        hipMemsetAsync(flags, 0, NVOX, stream);
        scatter_flags<<<(n + 255) / 256, 256, 0, stream>>>(ev, flags, n);
        expand_flags<<<(n4 + 255) / 256, 256, 0, stream>>>((const uchar4*)flags,
                                                           (fvec4*)d_out, n4);
    }
}

// Round 9
// 393.187 us; speedup vs baseline: 1.0719x; 1.0719x over previous
//
#include <hip/hip_runtime.h>

// Event voxelization: events [N,4] f32 (x,y,t,p) -> vox[2*16*260*346] set-to-1.
//
// R1-R6: any random per-event fabric access costs ~32-40 B (no write-allocate,
//        cache hints no-op, atomics serialize). R3's 183 us = that roofline.
// R7:    two-pass radix partition -> kernel sum ~125 us. (dur_us carries
//        ~265 us fixed harness reset: 1 GB ws poison + d_in restore.)
// R8:    register-resident idx[29] REGRESSED (+30 us): 29 VGPRs live across
//        the 16-barrier scan + unrolled atomic loop. LDS staging is cheaper.
// R9:    global per-bucket SEGMENTS: pass 1 reserves space via one atomicAdd
//        per bucket per WG, writes bucket-runs coalesced u16; pass 2 STREAMS
//        its segment (no goff table, no short-run gathers, full MLP).

#define CBINS 16
#define HDIM  260
#define WDIM  346
#define NVOX  (2 * CBINS * HDIM * WDIM)   // 2,878,720
#define NBUCK 256
#define RGN   11264                        // voxels/bucket; 256*11264 >= NVOX; < 2^16
#define CHUNK 7424                         // events per pass-1 WG
#define CAP   131072u                      // seg capacity/bucket (u16); 2.1x mean, binomial sigma ~250
#define SENT  0xFFFFFFFFu

typedef float fvec4 __attribute__((ext_vector_type(4)));

// -> (bucket<<16) | local_offset, or SENT if invalid. bucket<=255, local<RGN.
__device__ __forceinline__ unsigned ev_to_packed(fvec4 e) {
    float t = e.z;
    if (!(t > 0.f && t <= 1.f)) return SENT;
    int xi  = (int)e.x;
    int yi  = (int)e.y;
    int pi  = (e.w > 0.f) ? 1 : 0;                 // p {-1,1} -> {0,1}
    int bin = (int)ceilf(t * (float)CBINS) - 1;    // [0,15]
    unsigned idx = (unsigned)(xi + WDIM * yi + WDIM * HDIM * (bin + CBINS * pi));
    unsigned b = idx / (unsigned)RGN;              // const-div -> mulhi
    return (b << 16) | (idx - b * (unsigned)RGN);
}

// ---------------- Pass 1: partition into global bucket segments ----------------
__global__ __launch_bounds__(256) void partition_kernel(
        const fvec4* __restrict__ ev, int n,
        unsigned short* __restrict__ seg,    // [NBUCK * CAP] u16 local offsets
        unsigned* __restrict__ gcur) {       // [NBUCK] global cursors (pre-zeroed)
    __shared__ unsigned       raw[CHUNK];    // 29,696 B packed (b<<16|local)
    __shared__ unsigned short srt[CHUNK];    // 14,848 B bucket-sorted locals
    __shared__ unsigned hist[NBUCK + 1];
    __shared__ unsigned scan[NBUCK];
    __shared__ unsigned bnd[NBUCK + 1];      // srt bucket boundaries
    __shared__ unsigned cursor[NBUCK];
    __shared__ unsigned sbase[NBUCK];        // global segment base per bucket

    const int w = blockIdx.x, tid = threadIdx.x;
    const int base = w * CHUNK;
    const int nev = min(CHUNK, n - base);

    for (int b = tid; b <= NBUCK; b += 256) hist[b] = 0;
    __syncthreads();

    // Phase A: nt event loads (4x unrolled), pack -> LDS raw[], LDS histogram.
    int k = tid;
    for (; k + 768 < nev; k += 1024) {
        fvec4 e0 = __builtin_nontemporal_load(&ev[base + k]);
        fvec4 e1 = __builtin_nontemporal_load(&ev[base + k + 256]);
        fvec4 e2 = __builtin_nontemporal_load(&ev[base + k + 512]);
        fvec4 e3 = __builtin_nontemporal_load(&ev[base + k + 768]);
        unsigned i0 = ev_to_packed(e0), i1 = ev_to_packed(e1);
        unsigned i2 = ev_to_packed(e2), i3 = ev_to_packed(e3);
        raw[k]       = i0; raw[k + 256] = i1;
        raw[k + 512] = i2; raw[k + 768] = i3;
        atomicAdd(&hist[(i0 == SENT) ? NBUCK : (i0 >> 16)], 1u);
        atomicAdd(&hist[(i1 == SENT) ? NBUCK : (i1 >> 16)], 1u);
        atomicAdd(&hist[(i2 == SENT) ? NBUCK : (i2 >> 16)], 1u);
        atomicAdd(&hist[(i3 == SENT) ? NBUCK : (i3 >> 16)], 1u);
    }
    for (; k < nev; k += 256) {
        unsigned i0 = ev_to_packed(__builtin_nontemporal_load(&ev[base + k]));
        raw[k] = i0;
        atomicAdd(&hist[(i0 == SENT) ? NBUCK : (i0 >> 16)], 1u);
    }
    __syncthreads();

    // Phase B: inclusive scan (Hillis-Steele) + global segment reservation.
    unsigned v = hist[tid];
    scan[tid] = v;
    __syncthreads();
    for (int s = 1; s < 256; s <<= 1) {
        unsigned add = (tid >= s) ? scan[tid - s] : 0u;
        __syncthreads();
        scan[tid] += add;
        __syncthreads();
    }
    unsigned excl = scan[tid] - v;
    cursor[tid] = excl;
    bnd[tid] = excl;
    if (tid == 255) bnd[256] = scan[255];
    sbase[tid] = atomicAdd(&gcur[tid], v);   // one global atomic per bucket per WG
    __syncthreads();

    // Phase C: counting-sort u16 locals into LDS.
    for (k = tid; k < nev; k += 256) {
        unsigned vv = raw[k];
        if (vv != SENT) {
            unsigned pos = atomicAdd(&cursor[vv >> 16], 1u);
            srt[pos] = (unsigned short)(vv & 0xFFFFu);
        }
    }
    __syncthreads();

    // Phase D: wave-per-bucket coalesced u16 burst writes to global segments.
    const int wave = tid >> 6, lane = tid & 63;     // 4 waves x 64 buckets
    for (int b = wave * 64; b < wave * 64 + 64; ++b) {
        unsigned s = bnd[b], e = bnd[b + 1];        // broadcast LDS reads
        unsigned gb = sbase[b];
        unsigned short* dst = seg + (size_t)b * CAP;
        for (unsigned j = lane; j < e - s; j += 64) {
            unsigned d = gb + j;
            if (d < CAP) dst[d] = srt[s + j];       // clamp never fires (uniform input)
        }
    }
}

// ---------------- Pass 2: stream segment, flag in LDS, emit region ----------------
__global__ __launch_bounds__(1024) void build_kernel(
        const unsigned short* __restrict__ seg,
        const unsigned* __restrict__ gcur,
        fvec4* __restrict__ out) {
    __shared__ unsigned char flag[RGN];      // 11,264 B
    const int b = blockIdx.x, tid = threadIdx.x;

    for (int i = tid; i < RGN / 4; i += 1024) ((unsigned*)flag)[i] = 0;
    __syncthreads();

    unsigned n_b = min(gcur[b], CAP);        // entries in this bucket's segment
    const unsigned* p32 = (const unsigned*)(seg + (size_t)b * CAP);
    for (unsigned j = tid; j < n_b / 2; j += 1024) {   // coalesced streaming read
        unsigned v = __builtin_nontemporal_load(&p32[j]);
        flag[v & 0xFFFFu] = 1;
        flag[v >> 16]     = 1;
    }
    if (tid == 0 && (n_b & 1))
        flag[(seg + (size_t)b * CAP)[n_b - 1]] = 1;
    __syncthreads();

    for (int i = tid; i < RGN / 4; i += 1024) {
        int g = b * (RGN / 4) + i;                     // float4 index
        if (g < NVOX / 4) {
            uchar4 f = ((const uchar4*)flag)[i];
            fvec4 vv = { f.x ? 1.f : 0.f, f.y ? 1.f : 0.f,
                         f.z ? 1.f : 0.f, f.w ? 1.f : 0.f };
            __builtin_nontemporal_store(vv, &out[g]);
        }
    }
}

// ---------------- Fallback (R3 path) if ws too small ----------------
__global__ __launch_bounds__(256) void scatter_flags(const fvec4* __restrict__ ev,
                                                     unsigned char* __restrict__ flags,
                                                     int n) {
    int i = blockIdx.x * blockDim.x + threadIdx.x;
    if (i >= n) return;
    fvec4 e = __builtin_nontemporal_load(&ev[i]);
    float t = e.z;
    if (t > 0.f && t <= 1.f) {
        int xi = (int)e.x, yi = (int)e.y;
        int pi = (e.w > 0.f) ? 1 : 0;
        int bin = (int)ceilf(t * (float)CBINS) - 1;
        flags[xi + WDIM * yi + WDIM * HDIM * (bin + CBINS * pi)] = 1;
    }
}
__global__ __launch_bounds__(256) void expand_flags(const uchar4* __restrict__ flags,
                                                    fvec4* __restrict__ out, int n4) {
    int i = blockIdx.x * blockDim.x + threadIdx.x;
    if (i >= n4) return;
    uchar4 f = flags[i];
    fvec4 v = { f.x ? 1.f : 0.f, f.y ? 1.f : 0.f, f.z ? 1.f : 0.f, f.w ? 1.f : 0.f };
    __builtin_nontemporal_store(v, &out[i]);
}

extern "C" void kernel_launch(void* const* d_in, const int* in_sizes, int n_in,
                              void* d_out, int out_size, void* d_ws, size_t ws_size,
                              hipStream_t stream) {
    const fvec4* ev = (const fvec4*)d_in[0];
    int n  = in_sizes[0] / 4;                // 16,000,000
    int n4 = out_size / 4;                   // 719,680
    int nchunk = (n + CHUNK - 1) / CHUNK;    // 2156

    size_t seg_bytes = (size_t)NBUCK * CAP * sizeof(unsigned short);  // 64 MB
    size_t cur_bytes = NBUCK * sizeof(unsigned);

    if (ws_size >= seg_bytes + cur_bytes) {
        unsigned short* seg = (unsigned short*)d_ws;
        unsigned* gcur = (unsigned*)((char*)d_ws + seg_bytes);
        hipMemsetAsync(gcur, 0, cur_bytes, stream);
        partition_kernel<<<nchunk, 256, 0, stream>>>(ev, n, seg, gcur);
        build_kernel<<<NBUCK, 1024, 0, stream>>>(seg, gcur, (fvec4*)d_out);
    } else {
        unsigned char* flags = (unsigned char*)d_ws;
        hipMemsetAsync(flags, 0, NVOX, stream);
        scatter_flags<<<(n + 255) / 256, 256, 0, stream>>>(ev, flags, n);
        expand_flags<<<(n4 + 255) / 256, 256, 0, stream>>>((const uchar4*)flags,
                                                           (fvec4*)d_out, n4);
    }
}

// Round 10
// 388.364 us; speedup vs baseline: 1.0852x; 1.0124x over previous
//
#include <hip/hip_runtime.h>

// Event voxelization: events [N,4] f32 (x,y,t,p) -> vox[2*16*260*346] set-to-1.
//
// R1-R6: any random per-event fabric access costs ~32-40 B. R3 (183 us) = that
//        roofline. Cache hints / atomics / target size: all no-ops.
// R7/R9: two-pass radix partition -> kernel sum ~127 us (dur_us carries ~266 us
//        fixed harness reset). R8 (register-resident idx) regressed.
// R10:   cheaper pass 1: float-domain idx (exact < 2^24), wave-shuffle scan
//        (1 barrier vs 16), per-wave privatized histograms, 32-aligned segment
//        reservation (sentinel-padded) -> exclusive cache lines in Phase D.

#define CBINS 16
#define HDIM  260
#define WDIM  346
#define NVOX  (2 * CBINS * HDIM * WDIM)   // 2,878,720
#define NBUCK 256
#define RGN   11264                        // voxels/bucket; 256*11264 >= NVOX; < 2^16
#define CHUNK 7424                         // events per pass-1 WG
#define CAP   131072u                      // seg capacity/bucket (u16 entries)
#define SENT  0xFFFFFFFFu

typedef float fvec4 __attribute__((ext_vector_type(4)));

// -> (bucket<<16) | local_offset, or SENT. All idx math in fp32 (exact: <2^24).
__device__ __forceinline__ unsigned ev_to_packed(fvec4 e) {
    float t = e.z;
    if (!(t > 0.f && t <= 1.f)) return SENT;
    float bin = __builtin_ceilf(t * 16.f) - 1.f;          // [0,15]
    float bp  = (e.w > 0.f) ? (bin + 16.f) : bin;         // bin + 16*p
    float idxf = __builtin_fmaf(346.f, e.y, e.x);         // x + 346*y
    idxf = __builtin_fmaf(89960.f, bp, idxf);             // + W*H*16*(...)
    unsigned idx = (unsigned)idxf;
    unsigned b = idx / (unsigned)RGN;                     // mulhi+shift
    return (b << 16) | (idx - b * (unsigned)RGN);
}

// ---------------- Pass 1: partition into global bucket segments ----------------
__global__ __launch_bounds__(256) void partition_kernel(
        const fvec4* __restrict__ ev, int n,
        unsigned short* __restrict__ seg,    // [NBUCK * CAP] u16 local offsets
        unsigned* __restrict__ gcur) {       // [NBUCK] global cursors (pre-zeroed)
    __shared__ unsigned       raw[CHUNK];    // 29,696 B packed (b<<16|local)
    __shared__ unsigned short srt[CHUNK];    // 14,848 B bucket-sorted locals
    __shared__ unsigned hist4[4][NBUCK];     // 4,096 B per-wave histograms
    __shared__ unsigned bnd[NBUCK];          // srt bucket starts (excl scan)
    __shared__ unsigned lenA[NBUCK];         // bucket lengths
    __shared__ unsigned cursor[NBUCK];
    __shared__ unsigned sbase[NBUCK];        // global segment base per bucket
    __shared__ unsigned wsum[4];

    const int w = blockIdx.x, tid = threadIdx.x;
    const int wave = tid >> 6, lane = tid & 63;
    const int base = w * CHUNK;
    const int nev = min(CHUNK, n - base);

    hist4[0][tid >> 2 | ((tid & 3) << 6)] = 0;   // any full cover; cheap
    hist4[1][tid] = 0; hist4[2][tid] = 0; hist4[3][tid] = 0;
    hist4[0][tid] = 0;
    __syncthreads();

    // Phase A: nt event loads (4x unrolled), pack -> LDS raw[], per-wave hist.
    unsigned* myh = hist4[wave];
    int k = tid;
    for (; k + 768 < nev; k += 1024) {
        fvec4 e0 = __builtin_nontemporal_load(&ev[base + k]);
        fvec4 e1 = __builtin_nontemporal_load(&ev[base + k + 256]);
        fvec4 e2 = __builtin_nontemporal_load(&ev[base + k + 512]);
        fvec4 e3 = __builtin_nontemporal_load(&ev[base + k + 768]);
        unsigned i0 = ev_to_packed(e0), i1 = ev_to_packed(e1);
        unsigned i2 = ev_to_packed(e2), i3 = ev_to_packed(e3);
        raw[k]       = i0; raw[k + 256] = i1;
        raw[k + 512] = i2; raw[k + 768] = i3;
        if (i0 != SENT) atomicAdd(&myh[i0 >> 16], 1u);
        if (i1 != SENT) atomicAdd(&myh[i1 >> 16], 1u);
        if (i2 != SENT) atomicAdd(&myh[i2 >> 16], 1u);
        if (i3 != SENT) atomicAdd(&myh[i3 >> 16], 1u);
    }
    for (; k < nev; k += 256) {
        unsigned i0 = ev_to_packed(__builtin_nontemporal_load(&ev[base + k]));
        raw[k] = i0;
        if (i0 != SENT) atomicAdd(&myh[i0 >> 16], 1u);
    }
    __syncthreads();

    // Phase B: wave-shuffle inclusive scan over 256 bucket counts (1 barrier).
    unsigned val = hist4[0][tid] + hist4[1][tid] + hist4[2][tid] + hist4[3][tid];
    unsigned incl = val;
    #pragma unroll
    for (int s = 1; s < 64; s <<= 1) {
        unsigned u = __shfl_up(incl, s, 64);
        if (lane >= s) incl += u;
    }
    if (lane == 63) wsum[wave] = incl;
    __syncthreads();
    unsigned off = 0;
    if (wave > 0) off += wsum[0];
    if (wave > 1) off += wsum[1];
    if (wave > 2) off += wsum[2];
    unsigned excl = incl - val + off;
    bnd[tid]  = excl;
    lenA[tid] = val;
    cursor[tid] = excl;
    sbase[tid] = atomicAdd(&gcur[tid], (val + 31u) & ~31u);  // 32-aligned reserve
    __syncthreads();

    // Phase C: counting-sort u16 locals into LDS.
    for (k = tid; k < nev; k += 256) {
        unsigned vv = raw[k];
        if (vv != SENT) {
            unsigned pos = atomicAdd(&cursor[vv >> 16], 1u);
            srt[pos] = (unsigned short)(vv & 0xFFFFu);
        }
    }
    __syncthreads();

    // Phase D: wave-per-bucket aligned burst writes (pad -> sentinel RGN).
    for (int b = wave; b < NBUCK; b += 4) {
        unsigned s   = bnd[b], len = lenA[b];
        unsigned gb  = sbase[b];
        unsigned plen = (len + 31u) & ~31u;
        unsigned short* dst = seg + (size_t)b * CAP + gb;    // 64 B-aligned
        for (unsigned j = lane; j < plen; j += 64)
            dst[j] = (j < len) ? srt[s + j] : (unsigned short)RGN;
    }
}

// ---------------- Pass 2: stream segment, flag in LDS, emit region ----------------
__global__ __launch_bounds__(1024) void build_kernel(
        const unsigned short* __restrict__ seg,
        const unsigned* __restrict__ gcur,
        fvec4* __restrict__ out) {
    __shared__ unsigned char flag[12288];    // RGN + sentinel zone (flag[11264..])
    const int b = blockIdx.x, tid = threadIdx.x;

    for (int i = tid; i < 12288 / 4; i += 1024) ((unsigned*)flag)[i] = 0;
    __syncthreads();

    unsigned n_b = min(gcur[b], CAP);        // multiple of 32 -> even
    const unsigned* p32 = (const unsigned*)(seg + (size_t)b * CAP);
    for (unsigned j = tid; j < n_b / 2; j += 1024) {   // coalesced streaming read
        unsigned v = __builtin_nontemporal_load(&p32[j]);
        flag[v & 0xFFFFu] = 1;               // sentinel RGN -> flag[11264] (unused)
        flag[v >> 16]     = 1;
    }
    __syncthreads();

    for (int i = tid; i < RGN / 4; i += 1024) {
        int g = b * (RGN / 4) + i;                     // float4 index
        if (g < NVOX / 4) {
            uchar4 f = ((const uchar4*)flag)[i];
            fvec4 vv = { f.x ? 1.f : 0.f, f.y ? 1.f : 0.f,
                         f.z ? 1.f : 0.f, f.w ? 1.f : 0.f };
            __builtin_nontemporal_store(vv, &out[g]);
        }
    }
}

// ---------------- Fallback (R3 path) if ws too small ----------------
__global__ __launch_bounds__(256) void scatter_flags(const fvec4* __restrict__ ev,
                                                     unsigned char* __restrict__ flags,
                                                     int n) {
    int i = blockIdx.x * blockDim.x + threadIdx.x;
    if (i >= n) return;
    fvec4 e = __builtin_nontemporal_load(&ev[i]);
    float t = e.z;
    if (t > 0.f && t <= 1.f) {
        int xi = (int)e.x, yi = (int)e.y;
        int pi = (e.w > 0.f) ? 1 : 0;
        int bin = (int)ceilf(t * (float)CBINS) - 1;
        flags[xi + WDIM * yi + WDIM * HDIM * (bin + CBINS * pi)] = 1;
    }
}
__global__ __launch_bounds__(256) void expand_flags(const uchar4* __restrict__ flags,
                                                    fvec4* __restrict__ out, int n4) {
    int i = blockIdx.x * blockDim.x + threadIdx.x;
    if (i >= n4) return;
    uchar4 f = flags[i];
    fvec4 v = { f.x ? 1.f : 0.f, f.y ? 1.f : 0.f, f.z ? 1.f : 0.f, f.w ? 1.f : 0.f };
    __builtin_nontemporal_store(v, &out[i]);
}

extern "C" void kernel_launch(void* const* d_in, const int* in_sizes, int n_in,
                              void* d_out, int out_size, void* d_ws, size_t ws_size,
                              hipStream_t stream) {
    const fvec4* ev = (const fvec4*)d_in[0];
    int n  = in_sizes[0] / 4;                // 16,000,000
    int n4 = out_size / 4;                   // 719,680
    int nchunk = (n + CHUNK - 1) / CHUNK;    // 2156

    size_t seg_bytes = (size_t)NBUCK * CAP * sizeof(unsigned short);  // 64 MB
    size_t cur_bytes = NBUCK * sizeof(unsigned);

    if (ws_size >= seg_bytes + cur_bytes) {
        unsigned short* seg = (unsigned short*)d_ws;
        unsigned* gcur = (unsigned*)((char*)d_ws + seg_bytes);
        hipMemsetAsync(gcur, 0, cur_bytes, stream);
        partition_kernel<<<nchunk, 256, 0, stream>>>(ev, n, seg, gcur);
        build_kernel<<<NBUCK, 1024, 0, stream>>>(seg, gcur, (fvec4*)d_out);
    } else {
        unsigned char* flags = (unsigned char*)d_ws;
        hipMemsetAsync(flags, 0, NVOX, stream);
        scatter_flags<<<(n + 255) / 256, 256, 0, stream>>>(ev, flags, n);
        expand_flags<<<(n4 + 255) / 256, 256, 0, stream>>>((const uchar4*)flags,
                                                           (fvec4*)d_out, n4);
    }
}

// Round 11
// 381.215 us; speedup vs baseline: 1.1056x; 1.0188x over previous
//
#include <hip/hip_runtime.h>

// Event voxelization: events [N,4] f32 (x,y,t,p) -> vox[2*16*260*346] set-to-1.
//
// R1-R6: any random per-event fabric access costs ~32-40 B. R3 (183 us) = that
//        roofline; cache hints / atomics / target size all no-ops.
// R7/R9/R10: two-pass radix partition -> kernel sum ~122 us (total carries
//        ~266 us fixed harness reset). Scan/idx micro-opts nearly neutral.
// R11:   kill the counting-sort: STATIC per-bucket LDS slabs (256 x 64 u16).
//        One LDS atomic + one LDS write per event (vs 2 atomics + 5 LDS
//        touches). Poisson(29) overflow (P~1e-9/bucket-chunk) -> global
//        overflow list + fixup kernel (correct for adversarial input, free
//        for real input). LDS 52->35 KB (4 WGs/CU), no scan barriers.

#define CBINS 16
#define HDIM  260
#define WDIM  346
#define NVOX  (2 * CBINS * HDIM * WDIM)   // 2,878,720
#define NBUCK 256
#define RGN   11264                        // voxels/bucket; 256*11264 >= NVOX; < 2^16
#define CHUNK 7424                         // events per pass-1 WG (29/thread)
#define LCAP  64                           // slab capacity per bucket (u16)
#define SENT  0xFFFFFFFFu

typedef float fvec4 __attribute__((ext_vector_type(4)));

// -> (bucket<<16) | local_offset, or SENT. All idx math in fp32 (exact: <2^24).
__device__ __forceinline__ unsigned ev_to_packed(fvec4 e) {
    float t = e.z;
    if (!(t > 0.f && t <= 1.f)) return SENT;
    float bin = __builtin_ceilf(t * 16.f) - 1.f;          // [0,15]
    float bp  = (e.w > 0.f) ? (bin + 16.f) : bin;         // bin + 16*p
    float idxf = __builtin_fmaf(346.f, e.y, e.x);         // x + 346*y
    idxf = __builtin_fmaf(89960.f, bp, idxf);             // + W*H*16*(...)
    unsigned idx = (unsigned)idxf;
    unsigned b = idx / (unsigned)RGN;                     // mulhi+shift
    return (b << 16) | (idx - b * (unsigned)RGN);
}

// ---------------- Pass 1: slab-partition into global bucket segments ----------------
__global__ __launch_bounds__(256) void partition_kernel(
        const fvec4* __restrict__ ev, int n,
        unsigned short* __restrict__ seg,    // [NBUCK * cap] u16 local offsets
        unsigned* __restrict__ gcur,         // [NBUCK] cursors (pre-zeroed)
        unsigned* __restrict__ ovf,          // [0]=count, [1..] u32 voxel idx
        unsigned cap, unsigned ovf_cap) {
    __shared__ unsigned short slab[NBUCK * LCAP];   // 32,768 B
    __shared__ unsigned cnt[NBUCK];                 // 1,024 B
    __shared__ unsigned sbase[NBUCK];               // 1,024 B

    const int w = blockIdx.x, tid = threadIdx.x;
    const int wave = tid >> 6, lane = tid & 63;
    const int base = w * CHUNK;
    const int nev = min(CHUNK, n - base);

    cnt[tid] = 0;
    __syncthreads();

    // Phase A: nt event loads (4x unrolled for MLP); 1 LDS atomic + 1 LDS
    // write per valid event. Slab overflow -> global append (never on uniform).
    int k = tid;
    for (; k + 768 < nev; k += 1024) {
        fvec4 e0 = __builtin_nontemporal_load(&ev[base + k]);
        fvec4 e1 = __builtin_nontemporal_load(&ev[base + k + 256]);
        fvec4 e2 = __builtin_nontemporal_load(&ev[base + k + 512]);
        fvec4 e3 = __builtin_nontemporal_load(&ev[base + k + 768]);
        unsigned pk[4] = { ev_to_packed(e0), ev_to_packed(e1),
                           ev_to_packed(e2), ev_to_packed(e3) };
        #pragma unroll
        for (int q = 0; q < 4; ++q) {
            unsigned v = pk[q];
            if (v == SENT) continue;
            unsigned b = v >> 16;
            unsigned slot = atomicAdd(&cnt[b], 1u);
            if (slot < LCAP) slab[b * LCAP + slot] = (unsigned short)v;
            else {
                unsigned pos = atomicAdd(&ovf[0], 1u);
                if (pos < ovf_cap) ovf[1 + pos] = b * (unsigned)RGN + (v & 0xFFFFu);
            }
        }
    }
    for (; k < nev; k += 256) {
        unsigned v = ev_to_packed(__builtin_nontemporal_load(&ev[base + k]));
        if (v == SENT) continue;
        unsigned b = v >> 16;
        unsigned slot = atomicAdd(&cnt[b], 1u);
        if (slot < LCAP) slab[b * LCAP + slot] = (unsigned short)v;
        else {
            unsigned pos = atomicAdd(&ovf[0], 1u);
            if (pos < ovf_cap) ovf[1 + pos] = b * (unsigned)RGN + (v & 0xFFFFu);
        }
    }
    __syncthreads();

    // Phase B: 32-aligned global segment reservation (1 atomic per bucket).
    {
        unsigned len  = min(cnt[tid], (unsigned)LCAP);
        unsigned plen = (len + 31u) & ~31u;
        sbase[tid] = atomicAdd(&gcur[tid], plen);   // cap = nchunk*LCAP -> no overflow
    }
    __syncthreads();

    // Phase C: wave-per-bucket aligned burst writes (pad -> sentinel RGN).
    for (int b = wave; b < NBUCK; b += 4) {
        unsigned len  = min(cnt[b], (unsigned)LCAP);
        unsigned plen = (len + 31u) & ~31u;
        unsigned short* dst = seg + (size_t)b * cap + sbase[b];   // 64 B-aligned
        for (unsigned j = lane; j < plen; j += 64)
            dst[j] = (j < len) ? slab[b * LCAP + j] : (unsigned short)RGN;
    }
}

// ---------------- Pass 2: stream segment, flag in LDS, emit region ----------------
__global__ __launch_bounds__(1024) void build_kernel(
        const unsigned short* __restrict__ seg,
        const unsigned* __restrict__ gcur,
        fvec4* __restrict__ out, unsigned cap) {
    __shared__ unsigned char flag[12288];    // RGN + sentinel zone (flag[11264..])
    const int b = blockIdx.x, tid = threadIdx.x;

    for (int i = tid; i < 12288 / 4; i += 1024) ((unsigned*)flag)[i] = 0;
    __syncthreads();

    unsigned n_b = min(gcur[b], cap);        // multiple of 32 -> even
    const unsigned* p32 = (const unsigned*)(seg + (size_t)b * cap);
    for (unsigned j = tid; j < n_b / 2; j += 1024) {   // coalesced streaming read
        unsigned v = __builtin_nontemporal_load(&p32[j]);
        flag[v & 0xFFFFu] = 1;               // sentinel RGN -> flag[11264] (unused)
        flag[v >> 16]     = 1;
    }
    __syncthreads();

    for (int i = tid; i < RGN / 4; i += 1024) {
        int g = b * (RGN / 4) + i;                     // float4 index
        if (g < NVOX / 4) {
            uchar4 f = ((const uchar4*)flag)[i];
            fvec4 vv = { f.x ? 1.f : 0.f, f.y ? 1.f : 0.f,
                         f.z ? 1.f : 0.f, f.w ? 1.f : 0.f };
            __builtin_nontemporal_store(vv, &out[g]);
        }
    }
}

// ---------------- Pass 3: drain overflow list (empty on real input) ----------------
__global__ __launch_bounds__(256) void fixup_kernel(const unsigned* __restrict__ ovf,
                                                    float* __restrict__ out,
                                                    unsigned ovf_cap) {
    unsigned cnt = min(ovf[0], ovf_cap);
    for (unsigned j = blockIdx.x * blockDim.x + threadIdx.x; j < cnt;
         j += gridDim.x * blockDim.x)
        out[ovf[1 + j]] = 1.0f;
}

// ---------------- Fallback (R3 path) if ws too small ----------------
__global__ __launch_bounds__(256) void scatter_flags(const fvec4* __restrict__ ev,
                                                     unsigned char* __restrict__ flags,
                                                     int n) {
    int i = blockIdx.x * blockDim.x + threadIdx.x;
    if (i >= n) return;
    fvec4 e = __builtin_nontemporal_load(&ev[i]);
    float t = e.z;
    if (t > 0.f && t <= 1.f) {
        int xi = (int)e.x, yi = (int)e.y;
        int pi = (e.w > 0.f) ? 1 : 0;
        int bin = (int)ceilf(t * (float)CBINS) - 1;
        flags[xi + WDIM * yi + WDIM * HDIM * (bin + CBINS * pi)] = 1;
    }
}
__global__ __launch_bounds__(256) void expand_flags(const uchar4* __restrict__ flags,
                                                    fvec4* __restrict__ out, int n4) {
    int i = blockIdx.x * blockDim.x + threadIdx.x;
    if (i >= n4) return;
    uchar4 f = flags[i];
    fvec4 v = { f.x ? 1.f : 0.f, f.y ? 1.f : 0.f, f.z ? 1.f : 0.f, f.w ? 1.f : 0.f };
    __builtin_nontemporal_store(v, &out[i]);
}

extern "C" void kernel_launch(void* const* d_in, const int* in_sizes, int n_in,
                              void* d_out, int out_size, void* d_ws, size_t ws_size,
                              hipStream_t stream) {
    const fvec4* ev = (const fvec4*)d_in[0];
    int n  = in_sizes[0] / 4;                // 16,000,000
    int n4 = out_size / 4;                   // 719,680
    int nchunk = (n + CHUNK - 1) / CHUNK;    // 2156

    unsigned cap = (unsigned)nchunk * LCAP;  // per-bucket segment capacity (never overflows)
    unsigned ovf_cap = (unsigned)n;          // worst case: every event overflows
    size_t seg_bytes = (size_t)NBUCK * cap * sizeof(unsigned short);      // ~70.6 MB
    size_t cur_bytes = NBUCK * sizeof(unsigned);
    size_t ovf_bytes = (size_t)(1 + ovf_cap) * sizeof(unsigned);          // ~64 MB

    if (ws_size >= seg_bytes + cur_bytes + ovf_bytes) {
        unsigned short* seg = (unsigned short*)d_ws;
        unsigned* gcur = (unsigned*)((char*)d_ws + seg_bytes);
        unsigned* ovf  = gcur + NBUCK;       // [0]=count, entries follow
        hipMemsetAsync(gcur, 0, (NBUCK + 1) * sizeof(unsigned), stream);
        partition_kernel<<<nchunk, 256, 0, stream>>>(ev, n, seg, gcur, ovf, cap, ovf_cap);
        build_kernel<<<NBUCK, 1024, 0, stream>>>(seg, gcur, (fvec4*)d_out, cap);
        fixup_kernel<<<64, 256, 0, stream>>>(ovf, (float*)d_out, ovf_cap);
    } else {
        unsigned char* flags = (unsigned char*)d_ws;
        hipMemsetAsync(flags, 0, NVOX, stream);
        scatter_flags<<<(n + 255) / 256, 256, 0, stream>>>(ev, flags, n);
        expand_flags<<<(n4 + 255) / 256, 256, 0, stream>>>((const uchar4*)flags,
                                                           (fvec4*)d_out, n4);
    }
}

// Round 12
// 370.214 us; speedup vs baseline: 1.1384x; 1.0297x over previous
//
#include <hip/hip_runtime.h>

// Event voxelization: events [N,4] f32 (x,y,t,p) -> vox[2*16*260*346] set-to-1.
//
// R1-R6: any random per-event fabric access costs ~32-40 B. R3 (183 us) = that
//        roofline; cache hints / atomics / target size all no-ops.
// R7-R11: radix partition into per-bucket segments + LDS-flag build:
//        kernel sum ~115 us (total carries ~266 us fixed harness reset).
// R12:   CHUNK x2 (58 ev/thread) -> padding overhead 1.39->1.22x, half the WG
//        fixed costs; build reads uint4 (8 entries/load); fixup fused into
//        build (one fewer launch).

#define CBINS 16
#define HDIM  260
#define WDIM  346
#define NVOX  (2 * CBINS * HDIM * WDIM)   // 2,878,720
#define NBUCK 256
#define RGN   11264                        // voxels/bucket; 256*11264 >= NVOX; < 2^16
#define CHUNK 14848                        // events per pass-1 WG (58/thread)
#define LCAP  96                           // slab capacity per bucket (u16)
#define SENT  0xFFFFFFFFu

typedef float    fvec4 __attribute__((ext_vector_type(4)));
typedef unsigned uvec4 __attribute__((ext_vector_type(4)));

// -> (bucket<<16) | local_offset, or SENT. All idx math in fp32 (exact: <2^24).
__device__ __forceinline__ unsigned ev_to_packed(fvec4 e) {
    float t = e.z;
    if (!(t > 0.f && t <= 1.f)) return SENT;
    float bin = __builtin_ceilf(t * 16.f) - 1.f;          // [0,15]
    float bp  = (e.w > 0.f) ? (bin + 16.f) : bin;         // bin + 16*p
    float idxf = __builtin_fmaf(346.f, e.y, e.x);         // x + 346*y
    idxf = __builtin_fmaf(89960.f, bp, idxf);             // + W*H*16*(...)
    unsigned idx = (unsigned)idxf;
    unsigned b = idx / (unsigned)RGN;                     // mulhi+shift
    return (b << 16) | (idx - b * (unsigned)RGN);
}

// ---------------- Pass 1: slab-partition into global bucket segments ----------------
__global__ __launch_bounds__(256) void partition_kernel(
        const fvec4* __restrict__ ev, int n,
        unsigned short* __restrict__ seg,    // [NBUCK * cap] u16 local offsets
        unsigned* __restrict__ gcur,         // [NBUCK] cursors (pre-zeroed)
        unsigned* __restrict__ ovf,          // [0]=count, [1..] u32 voxel idx
        unsigned cap, unsigned ovf_cap) {
    __shared__ unsigned short slab[NBUCK * LCAP];   // 49,152 B
    __shared__ unsigned cnt[NBUCK];                 // 1,024 B
    __shared__ unsigned sbase[NBUCK];               // 1,024 B

    const int w = blockIdx.x, tid = threadIdx.x;
    const int wave = tid >> 6, lane = tid & 63;
    const int base = w * CHUNK;
    const int nev = min(CHUNK, n - base);

    cnt[tid] = 0;
    __syncthreads();

    // Phase A: nt event loads (4x unrolled for MLP); 1 LDS atomic + 1 LDS
    // write per valid event. Slab overflow -> global append (P ~ 1e-7).
    int k = tid;
    for (; k + 768 < nev; k += 1024) {
        fvec4 e0 = __builtin_nontemporal_load(&ev[base + k]);
        fvec4 e1 = __builtin_nontemporal_load(&ev[base + k + 256]);
        fvec4 e2 = __builtin_nontemporal_load(&ev[base + k + 512]);
        fvec4 e3 = __builtin_nontemporal_load(&ev[base + k + 768]);
        unsigned pk[4] = { ev_to_packed(e0), ev_to_packed(e1),
                           ev_to_packed(e2), ev_to_packed(e3) };
        #pragma unroll
        for (int q = 0; q < 4; ++q) {
            unsigned v = pk[q];
            if (v == SENT) continue;
            unsigned b = v >> 16;
            unsigned slot = atomicAdd(&cnt[b], 1u);
            if (slot < LCAP) slab[b * LCAP + slot] = (unsigned short)v;
            else {
                unsigned pos = atomicAdd(&ovf[0], 1u);
                if (pos < ovf_cap) ovf[1 + pos] = b * (unsigned)RGN + (v & 0xFFFFu);
            }
        }
    }
    for (; k < nev; k += 256) {
        unsigned v = ev_to_packed(__builtin_nontemporal_load(&ev[base + k]));
        if (v == SENT) continue;
        unsigned b = v >> 16;
        unsigned slot = atomicAdd(&cnt[b], 1u);
        if (slot < LCAP) slab[b * LCAP + slot] = (unsigned short)v;
        else {
            unsigned pos = atomicAdd(&ovf[0], 1u);
            if (pos < ovf_cap) ovf[1 + pos] = b * (unsigned)RGN + (v & 0xFFFFu);
        }
    }
    __syncthreads();

    // Phase B: 32-aligned global segment reservation (1 atomic per bucket).
    {
        unsigned len  = min(cnt[tid], (unsigned)LCAP);
        unsigned plen = (len + 31u) & ~31u;
        sbase[tid] = atomicAdd(&gcur[tid], plen);   // cap = nchunk*LCAP -> safe
    }
    __syncthreads();

    // Phase C: wave-per-bucket aligned burst writes (pad -> sentinel RGN).
    for (int b = wave; b < NBUCK; b += 4) {
        unsigned len  = min(cnt[b], (unsigned)LCAP);
        unsigned plen = (len + 31u) & ~31u;
        unsigned short* dst = seg + (size_t)b * cap + sbase[b];   // 64 B-aligned
        for (unsigned j = lane; j < plen; j += 64)
            dst[j] = (j < len) ? slab[b * LCAP + j] : (unsigned short)RGN;
    }
}

// ---------------- Pass 2: stream segment (uint4), flag in LDS, emit region ----------------
__global__ __launch_bounds__(1024) void build_kernel(
        const unsigned short* __restrict__ seg,
        const unsigned* __restrict__ gcur,
        const unsigned* __restrict__ ovf,
        fvec4* __restrict__ out, unsigned cap, unsigned ovf_cap) {
    __shared__ unsigned char flag[12288];    // RGN + sentinel zone (flag[11264..])
    const int b = blockIdx.x, tid = threadIdx.x;

    for (int i = tid; i < 12288 / 4; i += 1024) ((unsigned*)flag)[i] = 0;
    __syncthreads();

    unsigned n_b = min(gcur[b], cap);        // multiple of 32 entries (64 B)
    const uvec4* p128 = (const uvec4*)(seg + (size_t)b * cap);
    for (unsigned j = tid; j < n_b / 8; j += 1024) {   // uint4 = 8 u16 entries
        uvec4 v = __builtin_nontemporal_load(&p128[j]);
        flag[v.x & 0xFFFFu] = 1; flag[v.x >> 16] = 1;
        flag[v.y & 0xFFFFu] = 1; flag[v.y >> 16] = 1;
        flag[v.z & 0xFFFFu] = 1; flag[v.z >> 16] = 1;  // sentinel -> flag[11264]
        flag[v.w & 0xFFFFu] = 1; flag[v.w >> 16] = 1;
    }
    // Fused overflow drain (normally empty: one broadcast load + skip).
    unsigned oc = min(ovf[0], ovf_cap);
    unsigned rb = (unsigned)b * RGN;
    for (unsigned j = tid; j < oc; j += 1024) {
        unsigned g = ovf[1 + j];
        if (g - rb < (unsigned)RGN) flag[g - rb] = 1;
    }
    __syncthreads();

    for (int i = tid; i < RGN / 4; i += 1024) {
        int g = b * (RGN / 4) + i;                     // float4 index
        if (g < NVOX / 4) {
            uchar4 f = ((const uchar4*)flag)[i];
            fvec4 vv = { f.x ? 1.f : 0.f, f.y ? 1.f : 0.f,
                         f.z ? 1.f : 0.f, f.w ? 1.f : 0.f };
            __builtin_nontemporal_store(vv, &out[g]);
        }
    }
}

// ---------------- Fallback (R3 path) if ws too small ----------------
__global__ __launch_bounds__(256) void scatter_flags(const fvec4* __restrict__ ev,
                                                     unsigned char* __restrict__ flags,
                                                     int n) {
    int i = blockIdx.x * blockDim.x + threadIdx.x;
    if (i >= n) return;
    fvec4 e = __builtin_nontemporal_load(&ev[i]);
    float t = e.z;
    if (t > 0.f && t <= 1.f) {
        int xi = (int)e.x, yi = (int)e.y;
        int pi = (e.w > 0.f) ? 1 : 0;
        int bin = (int)ceilf(t * (float)CBINS) - 1;
        flags[xi + WDIM * yi + WDIM * HDIM * (bin + CBINS * pi)] = 1;
    }
}
__global__ __launch_bounds__(256) void expand_flags(const uchar4* __restrict__ flags,
                                                    fvec4* __restrict__ out, int n4) {
    int i = blockIdx.x * blockDim.x + threadIdx.x;
    if (i >= n4) return;
    uchar4 f = flags[i];
    fvec4 v = { f.x ? 1.f : 0.f, f.y ? 1.f : 0.f, f.z ? 1.f : 0.f, f.w ? 1.f : 0.f };
    __builtin_nontemporal_store(v, &out[i]);
}

extern "C" void kernel_launch(void* const* d_in, const int* in_sizes, int n_in,
                              void* d_out, int out_size, void* d_ws, size_t ws_size,
                              hipStream_t stream) {
    const fvec4* ev = (const fvec4*)d_in[0];
    int n  = in_sizes[0] / 4;                // 16,000,000
    int n4 = out_size / 4;                   // 719,680
    int nchunk = (n + CHUNK - 1) / CHUNK;    // 1078

    unsigned cap = (unsigned)nchunk * LCAP;  // per-bucket segment capacity
    unsigned ovf_cap = (unsigned)n;
    size_t seg_bytes = (size_t)NBUCK * cap * sizeof(unsigned short);      // ~53 MB
    size_t cur_bytes = NBUCK * sizeof(unsigned);
    size_t ovf_bytes = (size_t)(1 + ovf_cap) * sizeof(unsigned);          // ~64 MB

    if (ws_size >= seg_bytes + cur_bytes + ovf_bytes) {
        unsigned short* seg = (unsigned short*)d_ws;
        unsigned* gcur = (unsigned*)((char*)d_ws + seg_bytes);
        unsigned* ovf  = gcur + NBUCK;       // [0]=count, entries follow
        hipMemsetAsync(gcur, 0, (NBUCK + 1) * sizeof(unsigned), stream);
        partition_kernel<<<nchunk, 256, 0, stream>>>(ev, n, seg, gcur, ovf, cap, ovf_cap);
        build_kernel<<<NBUCK, 1024, 0, stream>>>(seg, gcur, ovf, (fvec4*)d_out,
                                                 cap, ovf_cap);
    } else {
        unsigned char* flags = (unsigned char*)d_ws;
        hipMemsetAsync(flags, 0, NVOX, stream);
        scatter_flags<<<(n + 255) / 256, 256, 0, stream>>>(ev, flags, n);
        expand_flags<<<(n4 + 255) / 256, 256, 0, stream>>>((const uchar4*)flags,
                                                           (fvec4*)d_out, n4);
    }
}